// Round 4
// baseline (295.928 us; speedup 1.0000x reference)
//
#include <hip/hip_runtime.h>
#include <hip/hip_bf16.h>
#include <cstdint>
#include <cstddef>

// ---------------------------------------------------------------------------
// bi_Mlp (fp32 I/O): out = binlin2( clip(gelu(binlin1(x))) )
// R3 -> R4:
//  * 32x32x16 bf16 MFMA (half the MFMA instructions per FLOP; m06/m119 show
//    ~17% higher pipe throughput than 16x16x32). Same LDS traffic, same
//    64 acc regs/lane (2x2 tiles x 16).
//  * GEMM2 tiled 64x128: 197x6 = 1182 blocks (was 594 = 2.3/CU, occupancy-
//    starved at 26%); M=12608 divides by 64 exactly -> no tail.
//  * XOR-swizzled LDS layout kept (R3: conflicts 2.19e7 -> 0).
// ---------------------------------------------------------------------------

typedef __bf16 bf16x8 __attribute__((ext_vector_type(8)));
typedef __bf16 bf16x4 __attribute__((ext_vector_type(4)));
typedef float floatx16 __attribute__((ext_vector_type(16)));

__device__ __forceinline__ void async_load16(const void* g, void* l) {
    __builtin_amdgcn_global_load_lds(
        (const __attribute__((address_space(1))) void*)g,
        (__attribute__((address_space(3))) void*)l,
        16, 0, 0);
}

// fp32 -> bf16 conversion, 4 elems/thread
__global__ __launch_bounds__(256) void x_to_bf16(
    const float* __restrict__ in, __hip_bfloat16* __restrict__ out, int n4)
{
    int i = blockIdx.x * 256 + threadIdx.x;
    if (i < n4) {
        float4 v = ((const float4*)in)[i];
        bf16x4 o;
        o[0] = (__bf16)v.x; o[1] = (__bf16)v.y;
        o[2] = (__bf16)v.z; o[3] = (__bf16)v.w;
        ((bf16x4*)out)[i] = o;
    }
}

// One block per row of W[rows, cols] (fp32): alpha[row] = mean|W[row,:]|,
// sgn[row,:] = sign(W) as exact bf16 (+1/-1/0). float4 loads.
__global__ __launch_bounds__(256) void bin_prep(
    const float* __restrict__ w,
    __hip_bfloat16* __restrict__ sgn,
    float* __restrict__ alpha,
    int cols4)  // cols/4
{
    const int row = blockIdx.x;
    const float4* wr = (const float4*)w + (size_t)row * cols4;
    bf16x4* sr = (bf16x4*)sgn + (size_t)row * cols4;
    float s = 0.0f;
    for (int c = threadIdx.x; c < cols4; c += 256) {
        float4 v = wr[c];
        s += fabsf(v.x) + fabsf(v.y) + fabsf(v.z) + fabsf(v.w);
        bf16x4 o;
        o[0] = (__bf16)(v.x > 0.0f ? 1.0f : (v.x < 0.0f ? -1.0f : 0.0f));
        o[1] = (__bf16)(v.y > 0.0f ? 1.0f : (v.y < 0.0f ? -1.0f : 0.0f));
        o[2] = (__bf16)(v.z > 0.0f ? 1.0f : (v.z < 0.0f ? -1.0f : 0.0f));
        o[3] = (__bf16)(v.w > 0.0f ? 1.0f : (v.w < 0.0f ? -1.0f : 0.0f));
        sr[c] = o;
    }
    #pragma unroll
    for (int off = 32; off > 0; off >>= 1) s += __shfl_down(s, off, 64);
    __shared__ float wsum[4];
    const int lane = threadIdx.x & 63;
    const int wv = threadIdx.x >> 6;
    if (lane == 0) wsum[wv] = s;
    __syncthreads();
    if (threadIdx.x == 0) {
        float t = wsum[0] + wsum[1] + wsum[2] + wsum[3];
        alpha[row] = t / (float)(cols4 * 4);
    }
}

__device__ __forceinline__ void store_val(__hip_bfloat16* C, size_t idx, float v) {
    C[idx] = __float2bfloat16(v);
}
__device__ __forceinline__ void store_val(float* C, size_t idx, float v) {
    C[idx] = v;
}

// C[M,N] = (A[M,K] . S[N,K]^T) * alpha[N] + bias[N]  (+ optional gelu/clip)
// Block tile TM x 128, K-step 64, 4 waves, 32x32x16 bf16 MFMA.
template <int TM, bool DO_GELU, typename OutT>
__global__ __launch_bounds__(256) void gemm_bin(
    const __hip_bfloat16* __restrict__ A,
    const __hip_bfloat16* __restrict__ S,
    const float* __restrict__ alpha,
    const float* __restrict__ bias,
    OutT* __restrict__ C,
    int M, int N, int K)
{
    constexpr int TN = 128;
    constexpr int TK = 64;
    constexpr int ASEG = TM / 8;          // 8-row A segments
    constexpr int RSEG = ASEG + TN / 8;   // total segments to stage
    constexpr int PW   = RSEG / 4;        // segments per wave
    constexpr int WMT  = TM / 2;          // wave tile M extent (64 or 32)
    constexpr int MI   = WMT / 32;        // 32-row tiles per wave in M (2 or 1)

    __shared__ __align__(16) __hip_bfloat16 sA[TM * TK];
    __shared__ __align__(16) __hip_bfloat16 sB[TN * TK];

    const int tid = threadIdx.x;
    const int wave = tid >> 6;
    const int lane = tid & 63;
    const int bm = blockIdx.y * TM;
    const int bn = blockIdx.x * TN;

    const int wm = (wave & 1) * WMT;      // wave M offset
    const int wn = (wave >> 1) * 64;      // wave N offset
    const int ln = lane & 31;             // row/col within 32-tile
    const int kh = lane >> 5;             // k-half (0/1) within 16-step
    const int e3 = lane & 7;              // swizzle class (== row&7 for reads)

    // staging: lane writes LDS offset lane*16B = row (lane>>3), slot (lane&7);
    // fetch global chunk (lane&7)^(lane>>3) so slot s of row r holds chunk s^(r&7)
    const int crow = lane >> 3;
    const int ccol = ((lane & 7) ^ crow) * 8;

    floatx16 acc[MI][2];
    #pragma unroll
    for (int i = 0; i < MI; i++)
        #pragma unroll
        for (int j = 0; j < 2; j++)
            #pragma unroll
            for (int r = 0; r < 16; r++)
                acc[i][j][r] = 0.0f;

    for (int k0 = 0; k0 < K; k0 += TK) {
        // --- stage A (TM rows) and B (128 rows) tiles, 16B/lane async
        #pragma unroll
        for (int t = 0; t < PW; t++) {
            const int seg = wave * PW + t;       // wave-uniform
            if (seg < ASEG) {
                const int r = seg * 8 + crow;
                int ar = bm + r;
                ar = ar < M ? ar : (M - 1);      // clamp tail rows (stores guarded)
                async_load16(A + (size_t)ar * K + (k0 + ccol), (void*)(sA + seg * 512));
            } else {
                const int r = (seg - ASEG) * 8 + crow;
                async_load16(S + (size_t)(bn + r) * K + (k0 + ccol),
                             (void*)(sB + (seg - ASEG) * 512));
            }
        }
        __syncthreads();

        // --- compute: 4 k-steps of 16, MI*2 MFMAs each (32x32x16)
        #pragma unroll
        for (int ks = 0; ks < 4; ks++) {
            // k-chunk kc = ks*2 + kh lives in slot kc ^ (row&7); row&7 == lane&7
            const int slot = ((ks * 2 + kh) ^ e3) * 8;
            bf16x8 af[MI], bfv[2];
            #pragma unroll
            for (int i = 0; i < MI; i++)
                af[i] = *(const bf16x8*)(sA + (wm + i * 32 + ln) * TK + slot);
            #pragma unroll
            for (int j = 0; j < 2; j++)
                bfv[j] = *(const bf16x8*)(sB + (wn + j * 32 + ln) * TK + slot);
            #pragma unroll
            for (int i = 0; i < MI; i++)
                #pragma unroll
                for (int j = 0; j < 2; j++)
                    acc[i][j] = __builtin_amdgcn_mfma_f32_32x32x16_bf16(
                        af[i], bfv[j], acc[i][j], 0, 0, 0);
        }
        __syncthreads();
    }

    // --- epilogue: C/D layout col=lane&31, row=(reg&3)+8*(reg>>2)+4*(lane>>5)
    float al[2], bi[2];
    #pragma unroll
    for (int j = 0; j < 2; j++) {
        const int col = bn + wn + j * 32 + ln;
        al[j] = alpha[col];
        bi[j] = bias[col];
    }
    #pragma unroll
    for (int i = 0; i < MI; i++) {
        #pragma unroll
        for (int r = 0; r < 16; r++) {
            const int row = bm + wm + i * 32 + (r & 3) + 8 * (r >> 2) + 4 * kh;
            if (row < M) {
                #pragma unroll
                for (int j = 0; j < 2; j++) {
                    float v = acc[i][j][r] * al[j] + bi[j];
                    if (DO_GELU) {
                        v = 0.5f * v * (1.0f + erff(v * 0.70710678118654752f));
                        v = fminf(fmaxf(v, -10.0f), 10.0f);
                    }
                    store_val(C, (size_t)row * N + (bn + wn + j * 32 + ln), v);
                }
            }
        }
    }
}

extern "C" void kernel_launch(void* const* d_in, const int* in_sizes, int n_in,
                              void* d_out, int out_size, void* d_ws, size_t ws_size,
                              hipStream_t stream) {
    const float* x  = (const float*)d_in[0];
    const float* w1 = (const float*)d_in[1];
    const float* b1 = (const float*)d_in[2];
    const float* w2 = (const float*)d_in[3];
    const float* b2 = (const float*)d_in[4];

    const int M = 64 * 197;   // 12608
    const int Cd = 768;
    const int Hd = 3072;

    // workspace layout (~106 MB total)
    char* ws = (char*)d_ws;
    __hip_bfloat16* xb   = (__hip_bfloat16*)ws;                 // [M, Cd]
    __hip_bfloat16* sgn1 = xb + (size_t)M * Cd;                 // [Hd, Cd]
    __hip_bfloat16* sgn2 = sgn1 + (size_t)Hd * Cd;              // [Cd, Hd]
    float* alpha1 = (float*)(sgn2 + (size_t)Cd * Hd);           // [Hd]
    float* alpha2 = alpha1 + Hd;                                // [Cd]
    __hip_bfloat16* hbuf = (__hip_bfloat16*)(alpha2 + Cd);      // [M, Hd]

    const int n4 = (M * Cd) / 4;
    x_to_bf16<<<(n4 + 255) / 256, 256, 0, stream>>>(x, xb, n4);
    bin_prep<<<Hd, 256, 0, stream>>>(w1, sgn1, alpha1, Cd / 4);
    bin_prep<<<Cd, 256, 0, stream>>>(w2, sgn2, alpha2, Hd / 4);

    // GEMM1: 128x128 tiles, 24x99 = 2376 blocks
    gemm_bin<128, true, __hip_bfloat16>
        <<<dim3(Hd / 128, (M + 127) / 128), 256, 0, stream>>>(
        xb, sgn1, alpha1, b1, hbuf, M, Hd, Cd);
    // GEMM2: 64x128 tiles, 6x197 = 1182 blocks (no M tail)
    gemm_bin<64, false, float>
        <<<dim3(Cd / 128, M / 64), 256, 0, stream>>>(
        hbuf, sgn2, alpha2, b2, (float*)d_out, M, Cd, Hd);
}

// Round 5
// 293.089 us; speedup vs baseline: 1.0097x; 1.0097x over previous
//
#include <hip/hip_runtime.h>
#include <hip/hip_bf16.h>
#include <cstdint>
#include <cstddef>

// ---------------------------------------------------------------------------
// bi_Mlp (fp32 I/O): out = binlin2( clip(gelu(binlin1(x))) )
// R4 -> R5:
//  * Revert to 16x16x32 MFMA read pattern (R3: measured ZERO bank conflicts;
//    R4's 32x32 k-selector lane>>5 created 4-way same-slot groups
//    {r,r+8,r+16,r+24} -> exactly +4 cyc per ds_read_b128 = 7.3e6 conflict
//    cycles = the 102->118 us regression).
//  * GEMM2 keeps TM=64 (1182 blocks vs 594; was occupancy-starved).
//  * cvt + both bin_preps merged into one launch (fewer gaps).
// ---------------------------------------------------------------------------

typedef __bf16 bf16x8 __attribute__((ext_vector_type(8)));
typedef __bf16 bf16x4 __attribute__((ext_vector_type(4)));
typedef float floatx4 __attribute__((ext_vector_type(4)));

__device__ __forceinline__ void async_load16(const void* g, void* l) {
    __builtin_amdgcn_global_load_lds(
        (const __attribute__((address_space(1))) void*)g,
        (__attribute__((address_space(3))) void*)l,
        16, 0, 0);
}

// Merged prep: blocks [0,ncvt) convert x fp32->bf16 (4 elem/thread);
// blocks [ncvt, ncvt+3072) binarize w1 row; rest binarize w2 row.
__global__ __launch_bounds__(256) void prep_all(
    const float* __restrict__ x,
    const float* __restrict__ w1,
    const float* __restrict__ w2,
    __hip_bfloat16* __restrict__ xb,
    __hip_bfloat16* __restrict__ sgn1, float* __restrict__ alpha1,
    __hip_bfloat16* __restrict__ sgn2, float* __restrict__ alpha2,
    int ncvt)
{
    const int b = blockIdx.x;
    if (b < ncvt) {
        const int i = b * 256 + threadIdx.x;   // ncvt*256 == n4 exactly
        float4 v = ((const float4*)x)[i];
        bf16x4 o;
        o[0] = (__bf16)v.x; o[1] = (__bf16)v.y;
        o[2] = (__bf16)v.z; o[3] = (__bf16)v.w;
        ((bf16x4*)xb)[i] = o;
        return;
    }
    const float* w; __hip_bfloat16* sgn; float* alpha; int cols4; int row;
    if (b < ncvt + 3072) {
        w = w1; sgn = sgn1; alpha = alpha1; cols4 = 192; row = b - ncvt;
    } else {
        w = w2; sgn = sgn2; alpha = alpha2; cols4 = 768; row = b - ncvt - 3072;
    }
    const float4* wr = (const float4*)w + (size_t)row * cols4;
    bf16x4* sr = (bf16x4*)sgn + (size_t)row * cols4;
    float s = 0.0f;
    for (int c = threadIdx.x; c < cols4; c += 256) {
        float4 v = wr[c];
        s += fabsf(v.x) + fabsf(v.y) + fabsf(v.z) + fabsf(v.w);
        bf16x4 o;
        o[0] = (__bf16)(v.x > 0.0f ? 1.0f : (v.x < 0.0f ? -1.0f : 0.0f));
        o[1] = (__bf16)(v.y > 0.0f ? 1.0f : (v.y < 0.0f ? -1.0f : 0.0f));
        o[2] = (__bf16)(v.z > 0.0f ? 1.0f : (v.z < 0.0f ? -1.0f : 0.0f));
        o[3] = (__bf16)(v.w > 0.0f ? 1.0f : (v.w < 0.0f ? -1.0f : 0.0f));
        sr[c] = o;
    }
    #pragma unroll
    for (int off = 32; off > 0; off >>= 1) s += __shfl_down(s, off, 64);
    __shared__ float wsum[4];
    const int lane = threadIdx.x & 63;
    const int wv = threadIdx.x >> 6;
    if (lane == 0) wsum[wv] = s;
    __syncthreads();
    if (threadIdx.x == 0) {
        float t = wsum[0] + wsum[1] + wsum[2] + wsum[3];
        alpha[row] = t / (float)(cols4 * 4);
    }
}

__device__ __forceinline__ void store_val(__hip_bfloat16* C, size_t idx, float v) {
    C[idx] = __float2bfloat16(v);
}
__device__ __forceinline__ void store_val(float* C, size_t idx, float v) {
    C[idx] = v;
}

// C[M,N] = (A[M,K] . S[N,K]^T) * alpha[N] + bias[N]  (+ optional gelu/clip)
// Block tile TM x 128, K-step 64, 4 waves (2x2), 16x16x32 bf16 MFMA.
// XOR-swizzled LDS: slot s of row r holds k-chunk s^(r&7) (R3: 0 conflicts).
template <int TM, bool DO_GELU, typename OutT>
__global__ __launch_bounds__(256) void gemm_bin(
    const __hip_bfloat16* __restrict__ A,
    const __hip_bfloat16* __restrict__ S,
    const float* __restrict__ alpha,
    const float* __restrict__ bias,
    OutT* __restrict__ C,
    int M, int N, int K)
{
    constexpr int TN = 128;
    constexpr int TK = 64;
    constexpr int WMT = TM / 2;          // wave M extent (64 or 32)
    constexpr int MI  = WMT / 16;        // 16-row tiles per wave (4 or 2)
    constexpr int ASEG = TM / 8;         // 8-row A segments (16 or 8)
    constexpr int RSEG = ASEG + TN / 8;  // total segments (32 or 24)
    constexpr int PW   = RSEG / 4;       // segments per wave (8 or 6)

    __shared__ __align__(16) __hip_bfloat16 sA[TM * TK];
    __shared__ __align__(16) __hip_bfloat16 sB[TN * TK];

    const int tid = threadIdx.x;
    const int wave = tid >> 6;
    const int lane = tid & 63;
    const int bm = blockIdx.y * TM;
    const int bn = blockIdx.x * TN;

    const int wm = (wave & 1) * WMT;
    const int wn = (wave >> 1) * 64;
    const int lr = lane & 15;         // m (A) / n (B) index within 16-tile
    const int kq = lane >> 4;         // 0..3: 8-elem k-chunk within 32-step
    const int e3 = lr & 7;            // swizzle class

    // staging: lane writes LDS offset lane*16B; fetch global chunk
    // (lane&7)^(lane>>3) so slot s of row r holds chunk s^(r&7)
    const int crow = lane >> 3;
    const int ccol = ((lane & 7) ^ crow) * 8;

    floatx4 acc[MI][4];
    #pragma unroll
    for (int i = 0; i < MI; i++)
        #pragma unroll
        for (int j = 0; j < 4; j++)
            #pragma unroll
            for (int r = 0; r < 4; r++)
                acc[i][j][r] = 0.0f;

    for (int k0 = 0; k0 < K; k0 += TK) {
        // --- stage A (TM rows) + B (128 rows), 16B/lane async
        #pragma unroll
        for (int t = 0; t < PW; t++) {
            const int seg = wave * PW + t;       // wave-uniform
            if (seg < ASEG) {
                const int r = seg * 8 + crow;
                int ar = bm + r;
                ar = ar < M ? ar : (M - 1);      // clamp tail rows (stores guarded)
                async_load16(A + (size_t)ar * K + (k0 + ccol), (void*)(sA + seg * 512));
            } else {
                const int r = (seg - ASEG) * 8 + crow;
                async_load16(S + (size_t)(bn + r) * K + (k0 + ccol),
                             (void*)(sB + (seg - ASEG) * 512));
            }
        }
        __syncthreads();

        // --- compute: 2 k-steps of 32, MI*4 MFMAs each
        #pragma unroll
        for (int ks = 0; ks < 2; ks++) {
            const int slot = ((ks << 2) | kq) ^ e3;   // k-chunk kc = ks*4+kq
            bf16x8 af[MI], bfv[4];
            #pragma unroll
            for (int i = 0; i < MI; i++)
                af[i] = *(const bf16x8*)(sA + (wm + i * 16 + lr) * TK + slot * 8);
            #pragma unroll
            for (int j = 0; j < 4; j++)
                bfv[j] = *(const bf16x8*)(sB + (wn + j * 16 + lr) * TK + slot * 8);
            #pragma unroll
            for (int i = 0; i < MI; i++)
                #pragma unroll
                for (int j = 0; j < 4; j++)
                    acc[i][j] = __builtin_amdgcn_mfma_f32_16x16x32_bf16(
                        af[i], bfv[j], acc[i][j], 0, 0, 0);
        }
        __syncthreads();
    }

    // --- epilogue: alpha/bias fp32, optional exact-erf gelu + clip
    float al[4], bi[4];
    #pragma unroll
    for (int j = 0; j < 4; j++) {
        const int col = bn + wn + j * 16 + lr;
        al[j] = alpha[col];
        bi[j] = bias[col];
    }
    #pragma unroll
    for (int i = 0; i < MI; i++) {
        const int row0 = bm + wm + i * 16 + kq * 4;
        #pragma unroll
        for (int r = 0; r < 4; r++) {
            const int row = row0 + r;
            if (row < M) {
                #pragma unroll
                for (int j = 0; j < 4; j++) {
                    float v = acc[i][j][r] * al[j] + bi[j];
                    if (DO_GELU) {
                        v = 0.5f * v * (1.0f + erff(v * 0.70710678118654752f));
                        v = fminf(fmaxf(v, -10.0f), 10.0f);
                    }
                    store_val(C, (size_t)row * N + (bn + wn + j * 16 + lr), v);
                }
            }
        }
    }
}

extern "C" void kernel_launch(void* const* d_in, const int* in_sizes, int n_in,
                              void* d_out, int out_size, void* d_ws, size_t ws_size,
                              hipStream_t stream) {
    const float* x  = (const float*)d_in[0];
    const float* w1 = (const float*)d_in[1];
    const float* b1 = (const float*)d_in[2];
    const float* w2 = (const float*)d_in[3];
    const float* b2 = (const float*)d_in[4];

    const int M = 64 * 197;   // 12608
    const int Cd = 768;
    const int Hd = 3072;

    // workspace layout (~106 MB total)
    char* ws = (char*)d_ws;
    __hip_bfloat16* xb   = (__hip_bfloat16*)ws;                 // [M, Cd]
    __hip_bfloat16* sgn1 = xb + (size_t)M * Cd;                 // [Hd, Cd]
    __hip_bfloat16* sgn2 = sgn1 + (size_t)Hd * Cd;              // [Cd, Hd]
    float* alpha1 = (float*)(sgn2 + (size_t)Cd * Hd);           // [Hd]
    float* alpha2 = alpha1 + Hd;                                // [Cd]
    __hip_bfloat16* hbuf = (__hip_bfloat16*)(alpha2 + Cd);      // [M, Hd]

    const int ncvt = (M * Cd) / 4 / 256;   // 9456 (exact)
    prep_all<<<ncvt + Hd + Cd, 256, 0, stream>>>(
        x, w1, w2, xb, sgn1, alpha1, sgn2, alpha2, ncvt);

    // GEMM1: 128x128 tiles, 24x99 = 2376 blocks
    gemm_bin<128, true, __hip_bfloat16>
        <<<dim3(Hd / 128, (M + 127) / 128), 256, 0, stream>>>(
        xb, sgn1, alpha1, b1, hbuf, M, Hd, Cd);
    // GEMM2: 64x128 tiles, 6x197 = 1182 blocks (no M tail)
    gemm_bin<64, false, float>
        <<<dim3(Cd / 128, M / 64), 256, 0, stream>>>(
        hbuf, sgn2, alpha2, b2, (float*)d_out, M, Cd, Hd);
}

// Round 6
// 260.909 us; speedup vs baseline: 1.1342x; 1.1233x over previous
//
#include <hip/hip_runtime.h>
#include <hip/hip_bf16.h>
#include <cstdint>
#include <cstddef>

// ---------------------------------------------------------------------------
// bi_Mlp (fp32 I/O): out = binlin2( clip(gelu(binlin1(x))) )
// R5 -> R6:
//  * GEMM2 back to TM=128 (R5's TM=64 measured 110 us vs <=102 at TM=128;
//    occupancy theory disproven, counter showed 3x FETCH overfetch instead).
//  * XCD-aware block swizzle, both GEMMs: blocks sharing an A-row-tile were
//    consecutive IDs -> spread round-robin over 8 XCD L2s -> each L2 filled
//    its own copy (GEMM2 FETCH 246 MB vs 82 ideal, GEMM1 85 vs 24). Remap
//    l=(b&7)*perXcd+(b>>3): each XCD owns a contiguous m-band, n-fastest, so
//    A-tile consumers are temporally adjacent on ONE XCD.
//  * 16x16x32 MFMA + XOR-swizzled LDS kept (0 bank conflicts measured).
// ---------------------------------------------------------------------------

typedef __bf16 bf16x8 __attribute__((ext_vector_type(8)));
typedef __bf16 bf16x4 __attribute__((ext_vector_type(4)));
typedef float floatx4 __attribute__((ext_vector_type(4)));

__device__ __forceinline__ void async_load16(const void* g, void* l) {
    __builtin_amdgcn_global_load_lds(
        (const __attribute__((address_space(1))) void*)g,
        (__attribute__((address_space(3))) void*)l,
        16, 0, 0);
}

// Merged prep: blocks [0,ncvt) convert x fp32->bf16 (4 elem/thread);
// blocks [ncvt, ncvt+3072) binarize w1 row; rest binarize w2 row.
__global__ __launch_bounds__(256) void prep_all(
    const float* __restrict__ x,
    const float* __restrict__ w1,
    const float* __restrict__ w2,
    __hip_bfloat16* __restrict__ xb,
    __hip_bfloat16* __restrict__ sgn1, float* __restrict__ alpha1,
    __hip_bfloat16* __restrict__ sgn2, float* __restrict__ alpha2,
    int ncvt)
{
    const int b = blockIdx.x;
    if (b < ncvt) {
        const int i = b * 256 + threadIdx.x;   // ncvt*256 == n4 exactly
        float4 v = ((const float4*)x)[i];
        bf16x4 o;
        o[0] = (__bf16)v.x; o[1] = (__bf16)v.y;
        o[2] = (__bf16)v.z; o[3] = (__bf16)v.w;
        ((bf16x4*)xb)[i] = o;
        return;
    }
    const float* w; __hip_bfloat16* sgn; float* alpha; int cols4; int row;
    if (b < ncvt + 3072) {
        w = w1; sgn = sgn1; alpha = alpha1; cols4 = 192; row = b - ncvt;
    } else {
        w = w2; sgn = sgn2; alpha = alpha2; cols4 = 768; row = b - ncvt - 3072;
    }
    const float4* wr = (const float4*)w + (size_t)row * cols4;
    bf16x4* sr = (bf16x4*)sgn + (size_t)row * cols4;
    float s = 0.0f;
    for (int c = threadIdx.x; c < cols4; c += 256) {
        float4 v = wr[c];
        s += fabsf(v.x) + fabsf(v.y) + fabsf(v.z) + fabsf(v.w);
        bf16x4 o;
        o[0] = (__bf16)(v.x > 0.0f ? 1.0f : (v.x < 0.0f ? -1.0f : 0.0f));
        o[1] = (__bf16)(v.y > 0.0f ? 1.0f : (v.y < 0.0f ? -1.0f : 0.0f));
        o[2] = (__bf16)(v.z > 0.0f ? 1.0f : (v.z < 0.0f ? -1.0f : 0.0f));
        o[3] = (__bf16)(v.w > 0.0f ? 1.0f : (v.w < 0.0f ? -1.0f : 0.0f));
        sr[c] = o;
    }
    #pragma unroll
    for (int off = 32; off > 0; off >>= 1) s += __shfl_down(s, off, 64);
    __shared__ float wsum[4];
    const int lane = threadIdx.x & 63;
    const int wv = threadIdx.x >> 6;
    if (lane == 0) wsum[wv] = s;
    __syncthreads();
    if (threadIdx.x == 0) {
        float t = wsum[0] + wsum[1] + wsum[2] + wsum[3];
        alpha[row] = t / (float)(cols4 * 4);
    }
}

__device__ __forceinline__ void store_val(__hip_bfloat16* C, size_t idx, float v) {
    C[idx] = __float2bfloat16(v);
}
__device__ __forceinline__ void store_val(float* C, size_t idx, float v) {
    C[idx] = v;
}

// C[M,N] = (A[M,K] . S[N,K]^T) * alpha[N] + bias[N]  (+ optional gelu/clip)
// 128x128 tile, K-step 64, 4 waves (2x2), 16x16x32 bf16 MFMA.
// XOR-swizzled LDS: slot s of row r holds k-chunk s^(r&7) (0 conflicts).
// 1-D grid, XCD-banded: l=(b&7)*perXcd+(b>>3); m = l/NT (band), n = l%NT.
template <bool DO_GELU, typename OutT>
__global__ __launch_bounds__(256) void gemm_bin(
    const __hip_bfloat16* __restrict__ A,
    const __hip_bfloat16* __restrict__ S,
    const float* __restrict__ alpha,
    const float* __restrict__ bias,
    OutT* __restrict__ C,
    int M, int N, int K, int T, int perXcd)
{
    constexpr int TM = 128;
    constexpr int TN = 128;
    constexpr int TK = 64;

    const int b = blockIdx.x;
    const int l = (b & 7) * perXcd + (b >> 3);
    if (l >= T) return;
    const int NT = N / TN;
    const int mt = l / NT;
    const int nt = l - mt * NT;
    const int bm = mt * TM;
    const int bn = nt * TN;

    __shared__ __align__(16) __hip_bfloat16 sA[TM * TK];
    __shared__ __align__(16) __hip_bfloat16 sB[TN * TK];

    const int tid = threadIdx.x;
    const int wave = tid >> 6;
    const int lane = tid & 63;

    const int wm = (wave & 1) * 64;
    const int wn = (wave >> 1) * 64;
    const int lr = lane & 15;         // m (A) / n (B) index within 16-tile
    const int kq = lane >> 4;         // 0..3: 8-elem k-chunk within 32-step
    const int e3 = lr & 7;            // swizzle class

    // staging: lane writes LDS offset lane*16B; fetch global chunk
    // (lane&7)^(lane>>3) so slot s of row r holds chunk s^(r&7)
    const int crow = lane >> 3;
    const int ccol = ((lane & 7) ^ crow) * 8;

    floatx4 acc[4][4];
    #pragma unroll
    for (int i = 0; i < 4; i++)
        #pragma unroll
        for (int j = 0; j < 4; j++)
            #pragma unroll
            for (int r = 0; r < 4; r++)
                acc[i][j][r] = 0.0f;

    for (int k0 = 0; k0 < K; k0 += TK) {
        // --- stage A (128 rows) + B (128 rows), 16B/lane async
        #pragma unroll
        for (int t = 0; t < 8; t++) {
            const int seg = wave * 8 + t;        // wave-uniform, 0..31
            if (seg < 16) {
                const int r = seg * 8 + crow;
                int ar = bm + r;
                ar = ar < M ? ar : (M - 1);      // clamp tail rows (stores guarded)
                async_load16(A + (size_t)ar * K + (k0 + ccol), (void*)(sA + seg * 512));
            } else {
                const int r = (seg - 16) * 8 + crow;
                async_load16(S + (size_t)(bn + r) * K + (k0 + ccol),
                             (void*)(sB + (seg - 16) * 512));
            }
        }
        __syncthreads();

        // --- compute: 2 k-steps of 32, 16 MFMAs each
        #pragma unroll
        for (int ks = 0; ks < 2; ks++) {
            const int slot = ((ks << 2) | kq) ^ e3;   // k-chunk kc = ks*4+kq
            bf16x8 af[4], bfv[4];
            #pragma unroll
            for (int i = 0; i < 4; i++)
                af[i] = *(const bf16x8*)(sA + (wm + i * 16 + lr) * TK + slot * 8);
            #pragma unroll
            for (int j = 0; j < 4; j++)
                bfv[j] = *(const bf16x8*)(sB + (wn + j * 16 + lr) * TK + slot * 8);
            #pragma unroll
            for (int i = 0; i < 4; i++)
                #pragma unroll
                for (int j = 0; j < 4; j++)
                    acc[i][j] = __builtin_amdgcn_mfma_f32_16x16x32_bf16(
                        af[i], bfv[j], acc[i][j], 0, 0, 0);
        }
        __syncthreads();
    }

    // --- epilogue: alpha/bias fp32, optional exact-erf gelu + clip
    float al[4], bi[4];
    #pragma unroll
    for (int j = 0; j < 4; j++) {
        const int col = bn + wn + j * 16 + lr;
        al[j] = alpha[col];
        bi[j] = bias[col];
    }
    #pragma unroll
    for (int i = 0; i < 4; i++) {
        const int row0 = bm + wm + i * 16 + kq * 4;
        #pragma unroll
        for (int r = 0; r < 4; r++) {
            const int row = row0 + r;
            if (row < M) {
                #pragma unroll
                for (int j = 0; j < 4; j++) {
                    float v = acc[i][j][r] * al[j] + bi[j];
                    if (DO_GELU) {
                        v = 0.5f * v * (1.0f + erff(v * 0.70710678118654752f));
                        v = fminf(fmaxf(v, -10.0f), 10.0f);
                    }
                    store_val(C, (size_t)row * N + (bn + wn + j * 16 + lr), v);
                }
            }
        }
    }
}

extern "C" void kernel_launch(void* const* d_in, const int* in_sizes, int n_in,
                              void* d_out, int out_size, void* d_ws, size_t ws_size,
                              hipStream_t stream) {
    const float* x  = (const float*)d_in[0];
    const float* w1 = (const float*)d_in[1];
    const float* b1 = (const float*)d_in[2];
    const float* w2 = (const float*)d_in[3];
    const float* b2 = (const float*)d_in[4];

    const int M = 64 * 197;   // 12608
    const int Cd = 768;
    const int Hd = 3072;

    // workspace layout (~106 MB total)
    char* ws = (char*)d_ws;
    __hip_bfloat16* xb   = (__hip_bfloat16*)ws;                 // [M, Cd]
    __hip_bfloat16* sgn1 = xb + (size_t)M * Cd;                 // [Hd, Cd]
    __hip_bfloat16* sgn2 = sgn1 + (size_t)Hd * Cd;              // [Cd, Hd]
    float* alpha1 = (float*)(sgn2 + (size_t)Cd * Hd);           // [Hd]
    float* alpha2 = alpha1 + Hd;                                // [Cd]
    __hip_bfloat16* hbuf = (__hip_bfloat16*)(alpha2 + Cd);      // [M, Hd]

    const int ncvt = (M * Cd) / 4 / 256;   // 9456 (exact)
    prep_all<<<ncvt + Hd + Cd, 256, 0, stream>>>(
        x, w1, w2, xb, sgn1, alpha1, sgn2, alpha2, ncvt);

    const int gm = (M + 127) / 128;        // 99

    // GEMM1: 24x99 = 2376 tiles; perXcd = 297 (exact)
    {
        const int T = (Hd / 128) * gm;
        const int perXcd = (T + 7) / 8;
        gemm_bin<true, __hip_bfloat16><<<perXcd * 8, 256, 0, stream>>>(
            xb, sgn1, alpha1, b1, hbuf, M, Hd, Cd, T, perXcd);
    }
    // GEMM2: 6x99 = 594 tiles; perXcd = 75, grid 600 (6 idle blocks)
    {
        const int T = (Cd / 128) * gm;
        const int perXcd = (T + 7) / 8;
        gemm_bin<false, float><<<perXcd * 8, 256, 0, stream>>>(
            hbuf, sgn2, alpha2, b2, (float*)d_out, M, Cd, Hd, T, perXcd);
    }
}